// Round 3
// baseline (771.188 us; speedup 1.0000x reference)
//
#include <hip/hip_runtime.h>

#define NN 100000
#define NE 1600000
#define BN_EPS 1e-5f
#define SCANB 25              // 25 blocks * 256 thr * 16 bins = 102400 >= NN
#define EDGE_BLOCKS 2048
#define EDGE_WAVES (EDGE_BLOCKS * 4)

typedef short s8v __attribute__((ext_vector_type(8)));
typedef float f4v __attribute__((ext_vector_type(4)));

__device__ __forceinline__ unsigned short f2bf(float f) {
  union { float f; unsigned u; } v; v.f = f;
  return (unsigned short)((v.u + 0x7FFFu + ((v.u >> 16) & 1u)) >> 16);
}

#define MFMA16(a, b, c) __builtin_amdgcn_mfma_f32_16x16x32_bf16((a), (b), (c), 0, 0, 0)

// ---------------------------------------------------------------------------
// x (f32) -> bf16 staging buffer
// ---------------------------------------------------------------------------
__global__ __launch_bounds__(256) void cvt_kernel(
    const float* __restrict__ xf, unsigned short* __restrict__ xb)
{
  const size_t i = (size_t)blockIdx.x * blockDim.x + threadIdx.x;
  if (i * 4 >= (size_t)NN * 64) return;
  float4 v = ((const float4*)xf)[i];
  ((ushort4*)xb)[i] = make_ushort4(f2bf(v.x), f2bf(v.y), f2bf(v.z), f2bf(v.w));
}

// ---------------------------------------------------------------------------
// Counting sort of edges by dst: hist -> block scan -> top scan -> add -> scatter
// ---------------------------------------------------------------------------
__global__ __launch_bounds__(256) void hist_kernel(
    const int* __restrict__ dstp, int* __restrict__ cnt)
{
  const int i = blockIdx.x * 256 + threadIdx.x;
  if (i < NE) atomicAdd(&cnt[dstp[i]], 1);
}

__global__ __launch_bounds__(256) void scan_blocks_kernel(
    const int* __restrict__ cnt, int* __restrict__ offsP, int* __restrict__ bsum)
{
  const int tid = threadIdx.x, lane = tid & 63, wv = tid >> 6;
  __shared__ int wsum[4], wbase[4];
  const int base = blockIdx.x * 4096 + tid * 16;
  int c[16]; int s = 0;
#pragma unroll
  for (int j = 0; j < 16; ++j) { int b = base + j; int v = (b < NN) ? cnt[b] : 0; c[j] = v; s += v; }
  int inc = s;
#pragma unroll
  for (int d = 1; d < 64; d <<= 1) { int v = __shfl_up(inc, d, 64); if (lane >= d) inc += v; }
  if (lane == 63) wsum[wv] = inc;
  __syncthreads();
  if (tid == 0) {
    int run = 0;
    for (int k = 0; k < 4; ++k) { int t = wsum[k]; wbase[k] = run; run += t; }
    bsum[blockIdx.x] = run;
  }
  __syncthreads();
  int run = wbase[wv] + inc - s;
#pragma unroll
  for (int j = 0; j < 16; ++j) { int b = base + j; if (b < NN) offsP[b] = run; run += c[j]; }
}

__global__ void scan_top_kernel(const int* __restrict__ bsum, int* __restrict__ bsum2)
{
  const int tid = threadIdx.x;               // 1 block, 64 threads
  int v = (tid < SCANB) ? bsum[tid] : 0;
  int inc = v;
#pragma unroll
  for (int d = 1; d < 64; d <<= 1) { int t = __shfl_up(inc, d, 64); if (tid >= d) inc += t; }
  if (tid < SCANB) bsum2[tid] = inc - v;
}

__global__ __launch_bounds__(256) void add_offsets_kernel(
    const int* __restrict__ offsP, const int* __restrict__ bsum2,
    int* __restrict__ offsF, int* __restrict__ cursor)
{
  const int i = blockIdx.x * 256 + threadIdx.x;
  if (i < NN) {
    int o = offsP[i] + bsum2[i >> 12];
    offsF[i] = o; cursor[i] = o;
  } else if (i == NN) {
    offsF[NN] = NE;
  }
}

__global__ __launch_bounds__(256) void scatter_kernel(
    const int* __restrict__ srcp, const int* __restrict__ dstp,
    int* __restrict__ cursor, int* __restrict__ s_src, int* __restrict__ s_dst)
{
  const int i = blockIdx.x * 256 + threadIdx.x;
  if (i < NE) {
    int d = dstp[i];
    int p = atomicAdd(&cursor[d], 1);
    s_dst[p] = d; s_src[p] = srcp[i];
  }
}

// ---------------------------------------------------------------------------
// Edge MLP over dst-sorted edges, node-aligned per-wave ranges:
// zero atomics — each wave owns all edges of its nodes, carries the open run
// in registers, stores each node's full sum exactly once.
// ---------------------------------------------------------------------------
__global__ __launch_bounds__(256) void edge_mlp_kernel(
    const unsigned short* __restrict__ xb,
    const int* __restrict__ s_src, const int* __restrict__ s_dst,
    const int* __restrict__ offsF,
    const float* __restrict__ W1, const float* __restrict__ b1,
    const float* __restrict__ a1p,
    const float* __restrict__ W2, const float* __restrict__ b2,
    const float* __restrict__ a2p,
    float* __restrict__ agg)
{
  const int lane = threadIdx.x & 63;
  const int wv   = threadIdx.x >> 6;
  const int q    = lane >> 4;
  const int r    = lane & 15;

  // Weight fragments: B[k=q*8+j][n=nt*16+r]
  s8v B1f[4][4];
  s8v B2f[2][4];
#pragma unroll
  for (int kk = 0; kk < 4; ++kk)
#pragma unroll
    for (int nt = 0; nt < 4; ++nt) {
      s8v f;
#pragma unroll
      for (int j = 0; j < 8; ++j)
        f[j] = (short)f2bf(W1[(kk * 32 + q * 8 + j) * 64 + nt * 16 + r]);
      B1f[kk][nt] = f;
    }
#pragma unroll
  for (int kk = 0; kk < 2; ++kk)
#pragma unroll
    for (int nt = 0; nt < 4; ++nt) {
      s8v f;
#pragma unroll
      for (int j = 0; j < 8; ++j)
        f[j] = (short)f2bf(W2[(kk * 32 + q * 8 + j) * 64 + nt * 16 + r]);
      B2f[kk][nt] = f;
    }

  float bias1[4], bias2[4];
#pragma unroll
  for (int nt = 0; nt < 4; ++nt) { bias1[nt] = b1[nt * 16 + r]; bias2[nt] = b2[nt * 16 + r]; }
  const float al1 = a1p[0];
  const float al2 = a2p[0];

  __shared__ __align__(16) unsigned short tbuf[4][16 * 72];  // layer1->layer2 transpose
  __shared__ __align__(16) float sbuf[4][16 * 66];           // per-edge h2 partials
  unsigned short* hb = tbuf[wv];
  float* S = sbuf[wv];

  // node-aligned edge range for this wave
  const int w = blockIdx.x * 4 + wv;
  const int t0 = (int)((long long)w * NE / EDGE_WAVES);
  const int t1 = (int)((long long)(w + 1) * NE / EDGE_WAVES);
  int lo = 0, hi = NN;
  while (lo < hi) { int mid = (lo + hi) >> 1; if (offsF[mid] < t0) lo = mid + 1; else hi = mid; }
  const int n0 = lo;
  lo = 0; hi = NN;
  while (lo < hi) { int mid = (lo + hi) >> 1; if (offsF[mid] < t1) lo = mid + 1; else hi = mid; }
  const int n1 = lo;
  const int start = offsF[n0], end = offsF[n1];

  int pdst = -1;                       // open-run dst (wave-uniform)
  float pv[4] = {0.f, 0.f, 0.f, 0.f};  // open-run partial, cols nt*16+r

  for (int e0 = start; e0 < end; e0 += 16) {
    const int e  = e0 + r;
    const int ec = e < end ? e : end - 1;
    const int dn = s_dst[ec];
    const int sn = s_src[ec];
    const s8v* xd = (const s8v*)(xb + (size_t)dn * 64);
    const s8v* xs = (const s8v*)(xb + (size_t)sn * 64);
    s8v a0  = xd[q];
    s8v a1v = xd[q + 4];
    s8v a2v = xs[q];
    s8v a3v = xs[q + 4];

    f4v acc[4];
#pragma unroll
    for (int nt = 0; nt < 4; ++nt) {
      f4v c = {0.f, 0.f, 0.f, 0.f};
      c = MFMA16(a0,  B1f[0][nt], c);
      c = MFMA16(a1v, B1f[1][nt], c);
      c = MFMA16(a2v, B1f[2][nt], c);
      c = MFMA16(a3v, B1f[3][nt], c);
      acc[nt] = c;
    }

#pragma unroll
    for (int nt = 0; nt < 4; ++nt)
#pragma unroll
      for (int rg = 0; rg < 4; ++rg) {
        float v = acc[nt][rg] + bias1[nt];
        v = v >= 0.f ? v : al1 * v;
        hb[(q * 4 + rg) * 72 + nt * 16 + r] = f2bf(v);
      }
    s8v p0 = *(const s8v*)(hb + r * 72 + q * 8);
    s8v p1 = *(const s8v*)(hb + r * 72 + 32 + q * 8);

    f4v acc2[4];
#pragma unroll
    for (int nt = 0; nt < 4; ++nt) {
      f4v c = {0.f, 0.f, 0.f, 0.f};
      c = MFMA16(p0, B2f[0][nt], c);
      c = MFMA16(p1, B2f[1][nt], c);
      acc2[nt] = c;
    }

    int drow[4];
#pragma unroll
    for (int rg = 0; rg < 4; ++rg) drow[rg] = __shfl(dn, q * 4 + rg, 64);

    // bias + prelu + validity mask
    float v[4][4];  // [nt][rg]
#pragma unroll
    for (int nt = 0; nt < 4; ++nt)
#pragma unroll
      for (int rg = 0; rg < 4; ++rg) {
        float x = acc2[nt][rg] + bias2[nt];
        x = x >= 0.f ? x : al2 * x;
        v[nt][rg] = (e0 + q * 4 + rg < end) ? x : 0.f;
      }

    // in-lane merge of adjacent rows with equal dst; write chunk-run partials
    int wr = 0;
    float cur[4];
#pragma unroll
    for (int nt = 0; nt < 4; ++nt) cur[nt] = v[nt][0];
#pragma unroll
    for (int rg = 1; rg < 4; ++rg) {
      if (drow[rg] == drow[rg - 1]) {
#pragma unroll
        for (int nt = 0; nt < 4; ++nt) cur[nt] += v[nt][rg];
      } else {
#pragma unroll
        for (int nt = 0; nt < 4; ++nt) S[(q * 4 + wr) * 66 + nt * 16 + r] = cur[nt];
        wr = rg;
#pragma unroll
        for (int nt = 0; nt < 4; ++nt) cur[nt] = v[nt][rg];
      }
    }
#pragma unroll
    for (int nt = 0; nt < 4; ++nt) S[(q * 4 + wr) * 66 + nt * 16 + r] = cur[nt];

    // run loop over the tile's 16 rows (wave-uniform branches).
    // Row m holds a partial iff (m&3)==0 or dst changes at m.
    for (int m = 0; m < 16; ++m) {
      const int dm = __shfl(dn, m, 64);
      if (dm != pdst) {
        if (pdst >= 0 && q == 0) {
#pragma unroll
          for (int nt = 0; nt < 4; ++nt)
            agg[(size_t)pdst * 64 + nt * 16 + r] = pv[nt];
        }
        pdst = dm;
#pragma unroll
        for (int nt = 0; nt < 4; ++nt) pv[nt] = S[m * 66 + nt * 16 + r];
      } else if ((m & 3) == 0) {
#pragma unroll
        for (int nt = 0; nt < 4; ++nt) pv[nt] += S[m * 66 + nt * 16 + r];
      }
    }
  }

  if (pdst >= 0 && q == 0) {
#pragma unroll
    for (int nt = 0; nt < 4; ++nt)
      agg[(size_t)pdst * 64 + nt * 16 + r] = pv[nt];
  }
}

// ---------------------------------------------------------------------------
// Node MLP: z = prelu(prelu(cat(x,agg) @ W3 + b3) @ W4 + b4, a_blk)
// ---------------------------------------------------------------------------
__global__ __launch_bounds__(256) void node_mlp_kernel(
    const unsigned short* __restrict__ xb,
    const float* __restrict__ agg,
    const float* __restrict__ W3, const float* __restrict__ b3,
    const float* __restrict__ a3p,
    const float* __restrict__ W4, const float* __restrict__ b4,
    const float* __restrict__ ablkp,
    float* __restrict__ zout,
    float* __restrict__ part)
{
  const int lane = threadIdx.x & 63;
  const int wv   = threadIdx.x >> 6;
  const int q    = lane >> 4;
  const int r    = lane & 15;
  const int wpb  = blockDim.x >> 6;
  const int nw   = gridDim.x * wpb;
  const int wid  = blockIdx.x * wpb + wv;

  s8v B3f[4][4];
  s8v B4f[2][4];
#pragma unroll
  for (int kk = 0; kk < 4; ++kk)
#pragma unroll
    for (int nt = 0; nt < 4; ++nt) {
      s8v f;
#pragma unroll
      for (int j = 0; j < 8; ++j)
        f[j] = (short)f2bf(W3[(kk * 32 + q * 8 + j) * 64 + nt * 16 + r]);
      B3f[kk][nt] = f;
    }
#pragma unroll
  for (int kk = 0; kk < 2; ++kk)
#pragma unroll
    for (int nt = 0; nt < 4; ++nt) {
      s8v f;
#pragma unroll
      for (int j = 0; j < 8; ++j)
        f[j] = (short)f2bf(W4[(kk * 32 + q * 8 + j) * 64 + nt * 16 + r]);
      B4f[kk][nt] = f;
    }

  float bias3[4], bias4[4];
#pragma unroll
  for (int nt = 0; nt < 4; ++nt) { bias3[nt] = b3[nt * 16 + r]; bias4[nt] = b4[nt * 16 + r]; }
  const float al3 = a3p[0];
  const float alb = ablkp[0];

  __shared__ __align__(16) unsigned short hbuf[4][16 * 72];
  unsigned short* hb = hbuf[wv];

  float bs[4] = {0.f, 0.f, 0.f, 0.f};
  float bq[4] = {0.f, 0.f, 0.f, 0.f};

  for (int t = wid; t < NN / 16; t += nw) {
    const int n = t * 16 + r;
    const s8v* xn = (const s8v*)(xb + (size_t)n * 64);
    s8v a0  = xn[q];
    s8v a1v = xn[q + 4];
    const f4v* an4 = (const f4v*)(agg + (size_t)n * 64);
    f4v g0 = an4[q * 2], g1 = an4[q * 2 + 1];
    f4v g2 = an4[8 + q * 2], g3 = an4[8 + q * 2 + 1];
    s8v a2v, a3v;
#pragma unroll
    for (int j = 0; j < 4; ++j) {
      a2v[j]     = (short)f2bf(g0[j]);
      a2v[4 + j] = (short)f2bf(g1[j]);
      a3v[j]     = (short)f2bf(g2[j]);
      a3v[4 + j] = (short)f2bf(g3[j]);
    }

    f4v acc[4];
#pragma unroll
    for (int nt = 0; nt < 4; ++nt) {
      f4v c = {0.f, 0.f, 0.f, 0.f};
      c = MFMA16(a0,  B3f[0][nt], c);
      c = MFMA16(a1v, B3f[1][nt], c);
      c = MFMA16(a2v, B3f[2][nt], c);
      c = MFMA16(a3v, B3f[3][nt], c);
      acc[nt] = c;
    }

#pragma unroll
    for (int nt = 0; nt < 4; ++nt)
#pragma unroll
      for (int rg = 0; rg < 4; ++rg) {
        float v = acc[nt][rg] + bias3[nt];
        v = v >= 0.f ? v : al3 * v;
        hb[(q * 4 + rg) * 72 + nt * 16 + r] = f2bf(v);
      }
    s8v p0 = *(const s8v*)(hb + r * 72 + q * 8);
    s8v p1 = *(const s8v*)(hb + r * 72 + 32 + q * 8);

    f4v acc2[4];
#pragma unroll
    for (int nt = 0; nt < 4; ++nt) {
      f4v c = {0.f, 0.f, 0.f, 0.f};
      c = MFMA16(p0, B4f[0][nt], c);
      c = MFMA16(p1, B4f[1][nt], c);
      acc2[nt] = c;
    }

#pragma unroll
    for (int nt = 0; nt < 4; ++nt)
#pragma unroll
      for (int rg = 0; rg < 4; ++rg) {
        float v = acc2[nt][rg] + bias4[nt];
        v = v >= 0.f ? v : alb * v;
        const int row = t * 16 + q * 4 + rg;
        zout[(size_t)row * 64 + nt * 16 + r] = v;
        bs[nt] += v;
        bq[nt] += v * v;
      }
  }

#pragma unroll
  for (int nt = 0; nt < 4; ++nt) {
    float s = bs[nt];
    s += __shfl_xor(s, 16, 64);
    s += __shfl_xor(s, 32, 64);
    float ss = bq[nt];
    ss += __shfl_xor(ss, 16, 64);
    ss += __shfl_xor(ss, 32, 64);
    if (q == 0) {
      atomicAdd(&part[nt * 16 + r], s);
      atomicAdd(&part[64 + nt * 16 + r], ss);
    }
  }
}

// ---------------------------------------------------------------------------
// BatchNorm finalize (in-place on d_out)
// ---------------------------------------------------------------------------
__global__ __launch_bounds__(256) void bn_kernel(
    float* __restrict__ out,
    const float* __restrict__ part,
    const float* __restrict__ gamma,
    const float* __restrict__ beta)
{
  const size_t i = (size_t)blockIdx.x * blockDim.x + threadIdx.x;
  if (i * 4 >= (size_t)NN * 64) return;
  float4 v = ((const float4*)out)[i];
  float e[4] = {v.x, v.y, v.z, v.w};
  const int f0 = (int)((i * 4) & 63);
  const float inv_n = 1.0f / (float)NN;
#pragma unroll
  for (int j = 0; j < 4; ++j) {
    const int f = f0 + j;
    const float mean = part[f] * inv_n;
    const float var  = part[64 + f] * inv_n - mean * mean;
    const float sc = rsqrtf(var + BN_EPS) * gamma[f];
    const float sh = beta[f] - mean * sc;
    e[j] = e[j] * sc + sh;
  }
  ((float4*)out)[i] = make_float4(e[0], e[1], e[2], e[3]);
}

extern "C" void kernel_launch(void* const* d_in, const int* in_sizes, int n_in,
                              void* d_out, int out_size, void* d_ws, size_t ws_size,
                              hipStream_t stream) {
  const float* x  = (const float*)d_in[0];
  const int* ei   = (const int*)d_in[1];
  const float* W1 = (const float*)d_in[2];
  const float* b1 = (const float*)d_in[3];
  const float* a1 = (const float*)d_in[4];
  const float* W2 = (const float*)d_in[5];
  const float* b2 = (const float*)d_in[6];
  const float* a2 = (const float*)d_in[7];
  const float* W3 = (const float*)d_in[8];
  const float* b3 = (const float*)d_in[9];
  const float* a3 = (const float*)d_in[10];
  const float* W4 = (const float*)d_in[11];
  const float* b4 = (const float*)d_in[12];
  const float* ab = (const float*)d_in[13];
  const float* gm = (const float*)d_in[14];
  const float* bt = (const float*)d_in[15];

  float* agg   = (float*)d_ws;                       // [NN*64] f32 (zeroed)
  float* part  = agg + (size_t)NN * 64;              // [128] f32 (zeroed)
  int* cnt     = (int*)(part + 128);                 // [NN] (zeroed)
  int* offsP   = cnt + NN;                           // [NN]
  int* offsF   = offsP + NN;                         // [NN+1] (+pad)
  int* cursor  = offsF + NN + 8;                     // [NN]
  int* bsum    = cursor + NN;                        // [32]
  int* bsum2   = bsum + 32;                          // [32]
  unsigned short* xb = (unsigned short*)(bsum2 + 32);// [NN*64] bf16
  int* s_dst   = (int*)(xb + (size_t)NN * 64);       // [NE]
  int* s_src   = s_dst + NE;                         // [NE]
  float* out   = (float*)d_out;

  const int* srcp = ei;        // edge_index[0]
  const int* dstp = ei + NE;   // edge_index[1]

  const size_t zero_bytes = ((size_t)NN * 64 + 128) * sizeof(float) + (size_t)NN * sizeof(int);
  hipMemsetAsync(d_ws, 0, zero_bytes, stream);

  cvt_kernel<<<dim3(6250), dim3(256), 0, stream>>>(x, xb);
  hist_kernel<<<dim3(6250), dim3(256), 0, stream>>>(dstp, cnt);
  scan_blocks_kernel<<<dim3(SCANB), dim3(256), 0, stream>>>(cnt, offsP, bsum);
  scan_top_kernel<<<dim3(1), dim3(64), 0, stream>>>(bsum, bsum2);
  add_offsets_kernel<<<dim3((NN + 1 + 255) / 256), dim3(256), 0, stream>>>(offsP, bsum2, offsF, cursor);
  scatter_kernel<<<dim3(6250), dim3(256), 0, stream>>>(srcp, dstp, cursor, s_src, s_dst);
  edge_mlp_kernel<<<dim3(EDGE_BLOCKS), dim3(256), 0, stream>>>(
      xb, s_src, s_dst, offsF, W1, b1, a1, W2, b2, a2, agg);
  node_mlp_kernel<<<dim3(1024), dim3(256), 0, stream>>>(
      xb, agg, W3, b3, a3, W4, b4, ab, out, part);
  bn_kernel<<<dim3(6250), dim3(256), 0, stream>>>(out, part, gm, bt);
}

// Round 4
// 520.217 us; speedup vs baseline: 1.4824x; 1.4824x over previous
//
#include <hip/hip_runtime.h>

#define NN 100000
#define NE 1600000
#define BN_EPS 1e-5f

typedef short s8v __attribute__((ext_vector_type(8)));
typedef float f4v __attribute__((ext_vector_type(4)));

__device__ __forceinline__ float bf2f(unsigned short u) {
  union { unsigned u; float f; } v; v.u = ((unsigned)u) << 16; return v.f;
}
__device__ __forceinline__ unsigned short f2bf(float f) {
  union { float f; unsigned u; } v; v.f = f;
  return (unsigned short)((v.u + 0x7FFFu + ((v.u >> 16) & 1u)) >> 16);
}

#define MFMA16(a, b, c) __builtin_amdgcn_mfma_f32_16x16x32_bf16((a), (b), (c), 0, 0, 0)

// ---------------------------------------------------------------------------
// Pre-GEMM: F = X @ W1[0:64,:]  (dst half),  G = X @ W1[64:128,:] (src half)
// stored bf16 row-major [NN][64].  ~1.6 GFLOP, one-shot.
// ---------------------------------------------------------------------------
__global__ __launch_bounds__(256) void pre_gemm_kernel(
    const float* __restrict__ x, const float* __restrict__ W1,
    unsigned short* __restrict__ F, unsigned short* __restrict__ G)
{
  const int lane = threadIdx.x & 63;
  const int wv   = threadIdx.x >> 6;
  const int q    = lane >> 4;
  const int r    = lane & 15;
  const int nw   = gridDim.x * 4;
  const int wid  = blockIdx.x * 4 + wv;

  // B-frags: B[k=kk*32+q*8+j][n=nt*16+r]; top = W1 rows 0..63, bot = rows 64..127
  s8v Bt[2][4], Bb[2][4];
#pragma unroll
  for (int kk = 0; kk < 2; ++kk)
#pragma unroll
    for (int nt = 0; nt < 4; ++nt) {
      s8v ft, fb;
#pragma unroll
      for (int j = 0; j < 8; ++j) {
        ft[j] = (short)f2bf(W1[(kk * 32 + q * 8 + j) * 64 + nt * 16 + r]);
        fb[j] = (short)f2bf(W1[(64 + kk * 32 + q * 8 + j) * 64 + nt * 16 + r]);
      }
      Bt[kk][nt] = ft; Bb[kk][nt] = fb;
    }

  for (int t = wid; t < NN / 16; t += nw) {
    const int n = t * 16 + r;
    const f4v* xp = (const f4v*)(x + (size_t)n * 64);
    f4v x0 = xp[q * 2],     x1 = xp[q * 2 + 1];
    f4v x2 = xp[8 + q * 2], x3 = xp[8 + q * 2 + 1];
    s8v a0, a1v;
#pragma unroll
    for (int j = 0; j < 4; ++j) {
      a0[j]      = (short)f2bf(x0[j]);
      a0[4 + j]  = (short)f2bf(x1[j]);
      a1v[j]     = (short)f2bf(x2[j]);
      a1v[4 + j] = (short)f2bf(x3[j]);
    }
    f4v aF[4], aG[4];
#pragma unroll
    for (int nt = 0; nt < 4; ++nt) {
      f4v c = {0.f, 0.f, 0.f, 0.f};
      c = MFMA16(a0,  Bt[0][nt], c);
      c = MFMA16(a1v, Bt[1][nt], c);
      aF[nt] = c;
      f4v d = {0.f, 0.f, 0.f, 0.f};
      d = MFMA16(a0,  Bb[0][nt], d);
      d = MFMA16(a1v, Bb[1][nt], d);
      aG[nt] = d;
    }
    // C-layout store: row = t*16 + q*4 + rg, col = nt*16 + r
#pragma unroll
    for (int nt = 0; nt < 4; ++nt)
#pragma unroll
      for (int rg = 0; rg < 4; ++rg) {
        const size_t idx = (size_t)(t * 16 + q * 4 + rg) * 64 + nt * 16 + r;
        F[idx] = f2bf(aF[nt][rg]);
        G[idx] = f2bf(aG[nt][rg]);
      }
  }
}

// ---------------------------------------------------------------------------
// Edge MLP v2: h1 = prelu(F[dst]+G[src]+b1) built directly in A-layout
// (no layer-1 MFMA, no LDS), then 8 MFMAs for layer 2, coalesced f32 atomics.
// ---------------------------------------------------------------------------
__global__ __launch_bounds__(256, 4) void edge_mlp_kernel(
    const unsigned short* __restrict__ F, const unsigned short* __restrict__ G,
    const int* __restrict__ ei,
    const float* __restrict__ b1, const float* __restrict__ a1p,
    const float* __restrict__ W2, const float* __restrict__ b2,
    const float* __restrict__ a2p,
    float* __restrict__ agg)
{
  const int lane = threadIdx.x & 63;
  const int wv   = threadIdx.x >> 6;
  const int q    = lane >> 4;
  const int r    = lane & 15;
  const int nw   = gridDim.x * 4;
  const int wid  = blockIdx.x * 4 + wv;

  s8v B2f[2][4];
#pragma unroll
  for (int kk = 0; kk < 2; ++kk)
#pragma unroll
    for (int nt = 0; nt < 4; ++nt) {
      s8v f;
#pragma unroll
      for (int j = 0; j < 8; ++j)
        f[j] = (short)f2bf(W2[(kk * 32 + q * 8 + j) * 64 + nt * 16 + r]);
      B2f[kk][nt] = f;
    }

  float b1f[16];
#pragma unroll
  for (int j = 0; j < 8; ++j) {
    b1f[j]     = b1[q * 8 + j];
    b1f[8 + j] = b1[32 + q * 8 + j];
  }
  float bias2[4];
#pragma unroll
  for (int nt = 0; nt < 4; ++nt) bias2[nt] = b2[nt * 16 + r];
  const float al1 = a1p[0];
  const float al2 = a2p[0];

  const int* __restrict__ srcp = ei;        // edge_index[0] = src (x_j)
  const int* __restrict__ dstp = ei + NE;   // edge_index[1] = dst (x_i)

  for (int t = wid; t < NE / 16; t += nw) {
    const int e  = t * 16 + r;
    const int dn = dstp[e];
    const int sn = srcp[e];
    s8v fa = *(const s8v*)(F + (size_t)dn * 64 + q * 8);
    s8v fb = *(const s8v*)(F + (size_t)dn * 64 + 32 + q * 8);
    s8v ga = *(const s8v*)(G + (size_t)sn * 64 + q * 8);
    s8v gb = *(const s8v*)(G + (size_t)sn * 64 + 32 + q * 8);

    s8v p0, p1;
#pragma unroll
    for (int j = 0; j < 8; ++j) {
      float v = bf2f((unsigned short)fa[j]) + bf2f((unsigned short)ga[j]) + b1f[j];
      v = v >= 0.f ? v : al1 * v;
      p0[j] = (short)f2bf(v);
      float w = bf2f((unsigned short)fb[j]) + bf2f((unsigned short)gb[j]) + b1f[8 + j];
      w = w >= 0.f ? w : al1 * w;
      p1[j] = (short)f2bf(w);
    }

    f4v acc2[4];
#pragma unroll
    for (int nt = 0; nt < 4; ++nt) {
      f4v c = {0.f, 0.f, 0.f, 0.f};
      c = MFMA16(p0, B2f[0][nt], c);
      c = MFMA16(p1, B2f[1][nt], c);
      acc2[nt] = c;
    }

    int drow[4];
#pragma unroll
    for (int rg = 0; rg < 4; ++rg) drow[rg] = __shfl(dn, q * 4 + rg, 64);

#pragma unroll
    for (int nt = 0; nt < 4; ++nt)
#pragma unroll
      for (int rg = 0; rg < 4; ++rg) {
        float v = acc2[nt][rg] + bias2[nt];
        v = v >= 0.f ? v : al2 * v;
        atomicAdd(&agg[(size_t)drow[rg] * 64 + nt * 16 + r], v);
      }
  }
}

// ---------------------------------------------------------------------------
// Node MLP: z = prelu(prelu(cat(x,agg) @ W3 + b3) @ W4 + b4, a_blk)
// reads x (f32) directly; writes z (f32) + BN partials
// ---------------------------------------------------------------------------
__global__ __launch_bounds__(256) void node_mlp_kernel(
    const float* __restrict__ x,
    const float* __restrict__ agg,
    const float* __restrict__ W3, const float* __restrict__ b3,
    const float* __restrict__ a3p,
    const float* __restrict__ W4, const float* __restrict__ b4,
    const float* __restrict__ ablkp,
    float* __restrict__ zout,
    float* __restrict__ part)
{
  const int lane = threadIdx.x & 63;
  const int wv   = threadIdx.x >> 6;
  const int q    = lane >> 4;
  const int r    = lane & 15;
  const int nw   = gridDim.x * 4;
  const int wid  = blockIdx.x * 4 + wv;

  s8v B3f[4][4];
  s8v B4f[2][4];
#pragma unroll
  for (int kk = 0; kk < 4; ++kk)
#pragma unroll
    for (int nt = 0; nt < 4; ++nt) {
      s8v f;
#pragma unroll
      for (int j = 0; j < 8; ++j)
        f[j] = (short)f2bf(W3[(kk * 32 + q * 8 + j) * 64 + nt * 16 + r]);
      B3f[kk][nt] = f;
    }
#pragma unroll
  for (int kk = 0; kk < 2; ++kk)
#pragma unroll
    for (int nt = 0; nt < 4; ++nt) {
      s8v f;
#pragma unroll
      for (int j = 0; j < 8; ++j)
        f[j] = (short)f2bf(W4[(kk * 32 + q * 8 + j) * 64 + nt * 16 + r]);
      B4f[kk][nt] = f;
    }

  float bias3[4], bias4[4];
#pragma unroll
  for (int nt = 0; nt < 4; ++nt) { bias3[nt] = b3[nt * 16 + r]; bias4[nt] = b4[nt * 16 + r]; }
  const float al3 = a3p[0];
  const float alb = ablkp[0];

  __shared__ __align__(16) unsigned short hbuf[4][16 * 72];
  unsigned short* hb = hbuf[wv];

  float bs[4] = {0.f, 0.f, 0.f, 0.f};
  float bq[4] = {0.f, 0.f, 0.f, 0.f};

  for (int t = wid; t < NN / 16; t += nw) {
    const int n = t * 16 + r;
    const f4v* xp = (const f4v*)(x + (size_t)n * 64);
    f4v x0 = xp[q * 2],     x1 = xp[q * 2 + 1];
    f4v x2 = xp[8 + q * 2], x3 = xp[8 + q * 2 + 1];
    const f4v* an4 = (const f4v*)(agg + (size_t)n * 64);
    f4v g0 = an4[q * 2],     g1 = an4[q * 2 + 1];
    f4v g2 = an4[8 + q * 2], g3 = an4[8 + q * 2 + 1];
    s8v a0, a1v, a2v, a3v;
#pragma unroll
    for (int j = 0; j < 4; ++j) {
      a0[j]      = (short)f2bf(x0[j]);
      a0[4 + j]  = (short)f2bf(x1[j]);
      a1v[j]     = (short)f2bf(x2[j]);
      a1v[4 + j] = (short)f2bf(x3[j]);
      a2v[j]     = (short)f2bf(g0[j]);
      a2v[4 + j] = (short)f2bf(g1[j]);
      a3v[j]     = (short)f2bf(g2[j]);
      a3v[4 + j] = (short)f2bf(g3[j]);
    }

    f4v acc[4];
#pragma unroll
    for (int nt = 0; nt < 4; ++nt) {
      f4v c = {0.f, 0.f, 0.f, 0.f};
      c = MFMA16(a0,  B3f[0][nt], c);
      c = MFMA16(a1v, B3f[1][nt], c);
      c = MFMA16(a2v, B3f[2][nt], c);
      c = MFMA16(a3v, B3f[3][nt], c);
      acc[nt] = c;
    }

#pragma unroll
    for (int nt = 0; nt < 4; ++nt)
#pragma unroll
      for (int rg = 0; rg < 4; ++rg) {
        float v = acc[nt][rg] + bias3[nt];
        v = v >= 0.f ? v : al3 * v;
        hb[(q * 4 + rg) * 72 + nt * 16 + r] = f2bf(v);
      }
    s8v p0 = *(const s8v*)(hb + r * 72 + q * 8);
    s8v p1 = *(const s8v*)(hb + r * 72 + 32 + q * 8);

    f4v acc2[4];
#pragma unroll
    for (int nt = 0; nt < 4; ++nt) {
      f4v c = {0.f, 0.f, 0.f, 0.f};
      c = MFMA16(p0, B4f[0][nt], c);
      c = MFMA16(p1, B4f[1][nt], c);
      acc2[nt] = c;
    }

#pragma unroll
    for (int nt = 0; nt < 4; ++nt)
#pragma unroll
      for (int rg = 0; rg < 4; ++rg) {
        float v = acc2[nt][rg] + bias4[nt];
        v = v >= 0.f ? v : alb * v;
        const int row = t * 16 + q * 4 + rg;
        zout[(size_t)row * 64 + nt * 16 + r] = v;
        bs[nt] += v;
        bq[nt] += v * v;
      }
  }

#pragma unroll
  for (int nt = 0; nt < 4; ++nt) {
    float s = bs[nt];
    s += __shfl_xor(s, 16, 64);
    s += __shfl_xor(s, 32, 64);
    float ss = bq[nt];
    ss += __shfl_xor(ss, 16, 64);
    ss += __shfl_xor(ss, 32, 64);
    if (q == 0) {
      atomicAdd(&part[nt * 16 + r], s);
      atomicAdd(&part[64 + nt * 16 + r], ss);
    }
  }
}

// ---------------------------------------------------------------------------
// BatchNorm finalize (in-place on d_out)
// ---------------------------------------------------------------------------
__global__ __launch_bounds__(256) void bn_kernel(
    float* __restrict__ out,
    const float* __restrict__ part,
    const float* __restrict__ gamma,
    const float* __restrict__ beta)
{
  const size_t i = (size_t)blockIdx.x * blockDim.x + threadIdx.x;
  if (i * 4 >= (size_t)NN * 64) return;
  float4 v = ((const float4*)out)[i];
  float e[4] = {v.x, v.y, v.z, v.w};
  const int f0 = (int)((i * 4) & 63);
  const float inv_n = 1.0f / (float)NN;
#pragma unroll
  for (int j = 0; j < 4; ++j) {
    const int f = f0 + j;
    const float mean = part[f] * inv_n;
    const float var  = part[64 + f] * inv_n - mean * mean;
    const float sc = rsqrtf(var + BN_EPS) * gamma[f];
    const float sh = beta[f] - mean * sc;
    e[j] = e[j] * sc + sh;
  }
  ((float4*)out)[i] = make_float4(e[0], e[1], e[2], e[3]);
}

extern "C" void kernel_launch(void* const* d_in, const int* in_sizes, int n_in,
                              void* d_out, int out_size, void* d_ws, size_t ws_size,
                              hipStream_t stream) {
  const float* x  = (const float*)d_in[0];
  const int* ei   = (const int*)d_in[1];
  const float* W1 = (const float*)d_in[2];
  const float* b1 = (const float*)d_in[3];
  const float* a1 = (const float*)d_in[4];
  const float* W2 = (const float*)d_in[5];
  const float* b2 = (const float*)d_in[6];
  const float* a2 = (const float*)d_in[7];
  const float* W3 = (const float*)d_in[8];
  const float* b3 = (const float*)d_in[9];
  const float* a3 = (const float*)d_in[10];
  const float* W4 = (const float*)d_in[11];
  const float* b4 = (const float*)d_in[12];
  const float* ab = (const float*)d_in[13];
  const float* gm = (const float*)d_in[14];
  const float* bt = (const float*)d_in[15];

  float* agg          = (float*)d_ws;                  // [NN*64] f32 (zeroed)
  float* part         = agg + (size_t)NN * 64;         // [128] f32 (zeroed)
  unsigned short* F   = (unsigned short*)(part + 128); // [NN*64] bf16
  unsigned short* G   = F + (size_t)NN * 64;           // [NN*64] bf16
  float* out          = (float*)d_out;

  hipMemsetAsync(d_ws, 0, ((size_t)NN * 64 + 128) * sizeof(float), stream);
  pre_gemm_kernel<<<dim3(1563), dim3(256), 0, stream>>>(x, W1, F, G);
  edge_mlp_kernel<<<dim3(4096), dim3(256), 0, stream>>>(F, G, ei, b1, a1, W2, b2, a2, agg);
  node_mlp_kernel<<<dim3(512), dim3(256), 0, stream>>>(x, agg, W3, b3, a3, W4, b4, ab, out, part);
  bn_kernel<<<dim3(6250), dim3(256), 0, stream>>>(out, part, gm, bt);
}